// Round 5
// baseline (529.394 us; speedup 1.0000x reference)
//
#include <hip/hip_runtime.h>
#include <hip/hip_bf16.h>

typedef unsigned short ushort_t;
typedef unsigned int u32;
typedef __attribute__((ext_vector_type(8))) short short8;
typedef short8 __attribute__((may_alias)) short8_ma;
typedef __attribute__((ext_vector_type(4))) float f32x4;
typedef f32x4 __attribute__((may_alias)) f32x4_ma;
typedef __attribute__((ext_vector_type(2))) unsigned int u32x2;
typedef u32x2 __attribute__((may_alias)) u32x2_ma;
typedef __attribute__((ext_vector_type(4))) unsigned int u32x4;
typedef u32x4 __attribute__((may_alias)) u32x4_ma;

#if __has_builtin(__builtin_amdgcn_exp2f)
#define EXP2(x) __builtin_amdgcn_exp2f(x)
#else
#define EXP2(x) exp2f(x)
#endif

__device__ __forceinline__ unsigned short f2bf(float f) {
    union { float f; unsigned int i; } x; x.f = f;
    unsigned int r = x.i + 0x7FFFu + ((x.i >> 16) & 1u);
    return (unsigned short)(r >> 16);
}
__device__ __forceinline__ unsigned int bfround(float f) {
    union { float f; unsigned int i; } x; x.f = f;
    return x.i + 0x7FFFu + ((x.i >> 16) & 1u);
}
// RNE bf16 pair packed in u32: [lo, hi] in memory order.
__device__ __forceinline__ unsigned int pack2bf(float lo, float hi) {
    return __builtin_amdgcn_perm(bfround(hi), bfround(lo), 0x07060302u);
}
// Single-instruction packed f32->bf16 (RNE): dst.lo = bf16(lo), dst.hi = bf16(hi).
__device__ __forceinline__ u32 cvtpk_bf16(float lo, float hi) {
    u32 r;
    asm("v_cvt_pk_bf16_f32 %0, %1, %2" : "=v"(r) : "v"(lo), "v"(hi));
    return r;
}
__device__ __forceinline__ f32x4 mfma16x16x32(short8 a, short8 b, f32x4 c) {
    return __builtin_amdgcn_mfma_f32_16x16x32_bf16(a, b, c, 0, 0, 0);
}
// Async global->LDS, 16B per lane. LDS dest = (wave-uniform base) + lane*16.
typedef const __attribute__((address_space(1))) u32 gu32;
typedef __attribute__((address_space(3))) u32 lu32;
__device__ __forceinline__ void async16(const ushort_t* g, ushort_t* l) {
    __builtin_amdgcn_global_load_lds((gu32*)g, (lu32*)l, 16, 0, 0);
}

// ---------------------------------------------------------------------------
// cast3: f32 -> bf16, 8 elements/thread, 3 tensors via blockIdx.z
// ---------------------------------------------------------------------------
__global__ __launch_bounds__(256)
void cast3(const float* __restrict__ A0, const float* __restrict__ A1,
           const float* __restrict__ A2, ushort_t* __restrict__ O0,
           ushort_t* __restrict__ O1, ushort_t* __restrict__ O2) {
    const float* A; ushort_t* O;
    switch (blockIdx.z) {
        case 0: A = A0; O = O0; break;
        case 1: A = A1; O = O1; break;
        default: A = A2; O = O2; break;
    }
    size_t idx = ((size_t)blockIdx.x * 256 + threadIdx.x) * 8;
    f32x4 v0 = *(const f32x4_ma*)(A + idx);
    f32x4 v1 = *(const f32x4_ma*)(A + idx + 4);
    u32x4 pk;
    pk[0] = pack2bf(v0[0], v0[1]);
    pk[1] = pack2bf(v0[2], v0[3]);
    pk[2] = pack2bf(v1[0], v1[1]);
    pk[3] = pack2bf(v1[2], v1[3]);
    *(u32x4_ma*)(O + idx) = pk;
}

// ---------------------------------------------------------------------------
// Weight transpose + f32->bf16: Wt[n][k] = bf16(W[k][n]), 1024x1024, 4 matrices
// ---------------------------------------------------------------------------
__global__ __launch_bounds__(256)
void transpose4(const float* __restrict__ W0, const float* __restrict__ W1,
                const float* __restrict__ W2, const float* __restrict__ W3,
                ushort_t* __restrict__ T0, ushort_t* __restrict__ T1,
                ushort_t* __restrict__ T2, ushort_t* __restrict__ T3) {
    __shared__ ushort_t tile[64][65];
    const float* W; ushort_t* T;
    switch (blockIdx.z) {
        case 0: W = W0; T = T0; break;
        case 1: W = W1; T = T1; break;
        case 2: W = W2; T = T2; break;
        default: W = W3; T = T3; break;
    }
    int bx = blockIdx.x * 64, by = blockIdx.y * 64;
    int tx = threadIdx.x & 63, ty = threadIdx.x >> 6;
    #pragma unroll
    for (int i = 0; i < 64; i += 4)
        tile[ty + i][tx] = f2bf(W[(size_t)(by + ty + i) * 1024 + bx + tx]);
    __syncthreads();
    #pragma unroll
    for (int i = 0; i < 64; i += 4)
        T[(size_t)(bx + ty + i) * 1024 + by + tx] = tile[tx][ty + i];
}

// ---------------------------------------------------------------------------
// GEMM (all-bf16 inputs): C[M,N] = A[M,K] @ Bt[N,K]^T + bias[N]
// 2-phase dbuf, global_load_lds, chunk^row&7 swizzle, T1 XCD-chunked block
// swizzle (XCD k owns M-panels [8k,8k+8) x all N-tiles; A+B L2-resident).
// MODE: 0 = bf16 C (outscale), 1 = f32 C, 2 = bf16 C^T scattered into
//   VtG[(b*16+h)*64+d][kr] (vtrans fused into the epilogue).
// ---------------------------------------------------------------------------
template<int MODE>
__global__ __launch_bounds__(256)
void gemm_async(const ushort_t* __restrict__ A, const ushort_t* __restrict__ Bt,
                const float* __restrict__ bias, void* __restrict__ Cab,
                int M, int N, int K, float outscale) {
    __shared__ __align__(16) ushort_t As[2][128 * 64];
    __shared__ __align__(16) ushort_t Bs[2][128 * 64];
    const int t = threadIdx.x;
    // grid is (8, 64): old = dispatch index; XCD = old & 7 (round-robin).
    const int old = blockIdx.x + (blockIdx.y << 3);
    const int neu = ((old & 7) << 6) | (old >> 3);   // bijective, 512 blocks
    const int n0 = (neu & 7) * 128, m0 = (neu >> 3) * 128;
    const int w = t >> 6, lane = t & 63, quad = lane >> 4, lr = lane & 15;
    const int wm = (w >> 1) * 64, wn = (w & 1) * 64;
    const int lrow8 = lane >> 3, lchunk = lane & 7;
    const int sw = (lchunk ^ lrow8) * 8;

    f32x4 acc[4][4] = {};

    #define STAGEAB(dst, koff) do { \
        _Pragma("unroll") \
        for (int i_ = 0; i_ < 4; i_++) { \
            int ra_ = 32 * w + 8 * i_ + lrow8; \
            async16(A  + (size_t)(m0 + ra_) * K + (koff) + sw, &As[dst][(32 * w + 8 * i_) * 64]); \
            async16(Bt + (size_t)(n0 + ra_) * K + (koff) + sw, &Bs[dst][(32 * w + 8 * i_) * 64]); \
        } } while (0)

    STAGEAB(0, 0);

    int cur = 0;
    for (int k0 = 0; k0 < K; k0 += 64) {
        __syncthreads();   // drains vmcnt: buf[cur] ready
        if (k0 + 64 < K)
            STAGEAB(cur ^ 1, k0 + 64);
        #pragma unroll
        for (int kc = 0; kc < 2; kc++) {
            short8 af[4], bf[4];
            int pa = ((4 * kc + quad) ^ (lr & 7)) * 8;
            #pragma unroll
            for (int i = 0; i < 4; i++) {
                af[i] = *(const short8_ma*)(As[cur] + (wm + i * 16 + lr) * 64 + pa);
                bf[i] = *(const short8_ma*)(Bs[cur] + (wn + i * 16 + lr) * 64 + pa);
            }
            #pragma unroll
            for (int i = 0; i < 4; i++)
                #pragma unroll
                for (int j = 0; j < 4; j++)
                    acc[i][j] = mfma16x16x32(af[i], bf[j], acc[i][j]);
        }
        cur ^= 1;
    }
    #undef STAGEAB

    // Epilogue: C/D layout row = quad*4 + reg, col = lane&15
    #pragma unroll
    for (int i = 0; i < 4; i++) {
        int row = m0 + wm + i * 16 + quad * 4;
        #pragma unroll
        for (int j = 0; j < 4; j++) {
            int col = n0 + wn + j * 16 + lr;
            float bv = bias[col];
            if (MODE == 2) {
                // VtG[(b*16 + h)*64 + d][kr], b=row>>11, kr=row&2047,
                // h=col>>6, d=col&63. r=0..3 are consecutive kr.
                u32x2 pw;
                pw[0] = cvtpk_bf16(acc[i][j][0] + bv, acc[i][j][1] + bv);
                pw[1] = cvtpk_bf16(acc[i][j][2] + bv, acc[i][j][3] + bv);
                size_t vrow = (size_t)(((row >> 11) << 4) | (col >> 6)) * 64 + (col & 63);
                *(u32x2_ma*)((ushort_t*)Cab + vrow * 2048 + (row & 2047)) = pw;
            } else {
                #pragma unroll
                for (int r = 0; r < 4; r++) {
                    size_t idx = (size_t)(row + r) * N + col;
                    if (MODE == 1) ((float*)Cab)[idx] = acc[i][j][r] + bv;
                    else ((ushort_t*)Cab)[idx] = f2bf((acc[i][j][r] + bv) * outscale);
                }
            }
        }
    }
}

// ---------------------------------------------------------------------------
// Flash attention, static-max + ZERO-STAGING variant.
// R4 counters: HBM 4.6%, MfmaUtil 26%, ~21% dual-idle, occupancy 2 blocks/CU
// (LDS-capped at 48KB) -> still latency-bound. K/V are L2-resident per XCD
// (FETCH 24.6MB proved it), so LDS staging + its barriers are pure overhead
// (guide m169: dropping V-staging at L2-fit was +26%).
// This round: read K and V fragments DIRECTLY from global (same algebra as
// the staged reads, swizzle collapses out). Removes ALL barriers and ALL
// async16 from the kt loop -> waves free-run; LDS = Pt only (16KB) -> up to
// 4 blocks/CU. V loads issued before softmax so L2 latency hides under VALU.
// ---------------------------------------------------------------------------
__global__ __launch_bounds__(256)
void attn_fwd(const ushort_t* __restrict__ Q, const ushort_t* __restrict__ Kg,
              const ushort_t* __restrict__ VtG, ushort_t* __restrict__ Z) {
    __shared__ __align__(16) ushort_t Pt[128 * 64];     // [qrow][krow] (wave-private rows)

    const int t = threadIdx.x;
    // grid is (16, 64): old = dispatch index; XCD = old & 7.
    const int old = blockIdx.x + (blockIdx.y << 4);
    const int neu = ((old & 7) << 7) | (old >> 3);   // bijective, 1024 blocks
    const int qt = neu & 15;          // 0..15
    const int bh = neu >> 4;          // 0..63
    const int b = bh >> 4, h = bh & 15;
    const int w = t >> 6, lane = t & 63, quad = lane >> 4, lr = lane & 15;

    const size_t rs = 1024;
    const size_t qbase = ((size_t)b * 2048 + qt * 128) * rs + h * 64;
    const size_t kvbase = ((size_t)b * 2048) * rs + h * 64;
    const size_t vbase = (size_t)bh * 64 * 2048;

    // Q fragments (B-operand of S^T: n = lr = qrow, k = quad*8+j = d)
    short8 qf[2][2];
    #pragma unroll
    for (int mt = 0; mt < 2; mt++)
        #pragma unroll
        for (int kc = 0; kc < 2; kc++)
            qf[mt][kc] = *(const short8_ma*)(Q + qbase + (size_t)(w * 32 + mt * 16 + lr) * rs + kc * 32 + quad * 8);

    f32x4 oacc[2][4] = {};   // oacc[mt][dn] = O^T[d = dn*16+quad*4+r][qrow = w*32+mt*16+lr]
    float lsum[2] = { 0.f, 0.f };   // per-lane partial of sum(P) (reduced in epilogue)

    // K fragment row base: row (kt*64 + nt*16 + lr), d-offset (4*kc+quad)*8
    const ushort_t* kp = Kg + kvbase + (size_t)lr * rs + quad * 8;
    // V fragment row base: row (dn*16+lr) of [64][2048], kr-offset kt*64 + (4*kc2+quad)*8
    const ushort_t* vp = VtG + vbase + (size_t)lr * 2048 + quad * 8;

    for (int kt = 0; kt < 32; kt++) {
        // S^T = K.Q^T : sacc[nt][mt] rows = krow (nt*16+quad*4+r), cols = qrow (mt*16+lr)
        f32x4 sacc[4][2] = {};
        #pragma unroll
        for (int kc = 0; kc < 2; kc++) {
            short8 kf[4];
            #pragma unroll
            for (int nt = 0; nt < 4; nt++)
                kf[nt] = *(const short8_ma*)(kp + (size_t)(kt * 64 + nt * 16) * rs + kc * 32);
            #pragma unroll
            for (int nt = 0; nt < 4; nt++)
                #pragma unroll
                for (int mt = 0; mt < 2; mt++)
                    sacc[nt][mt] = mfma16x16x32(kf[nt], qf[mt][kc], sacc[nt][mt]);
        }

        // Issue V fragment loads now (global, L2-resident): their latency
        // hides under the softmax VALU phase below.
        short8 vf[2][4];
        #pragma unroll
        for (int kc2 = 0; kc2 < 2; kc2++)
            #pragma unroll
            for (int dn = 0; dn < 4; dn++)
                vf[kc2][dn] = *(const short8_ma*)(vp + (size_t)(dn * 16) * 2048 + kt * 64 + kc2 * 32);

        // static-max softmax: P = exp2(s) directly; no cross-lane ops, no branch
        #pragma unroll
        for (int mt = 0; mt < 2; mt++) {
            const int prow = w * 32 + mt * 16 + lr;
            #pragma unroll
            for (int nt = 0; nt < 4; nt++) {
                float p0 = EXP2(sacc[nt][mt][0]);
                float p1 = EXP2(sacc[nt][mt][1]);
                float p2 = EXP2(sacc[nt][mt][2]);
                float p3 = EXP2(sacc[nt][mt][3]);
                lsum[mt] += (p0 + p1) + (p2 + p3);
                u32x2 pw;
                pw[0] = cvtpk_bf16(p0, p1);
                pw[1] = cvtpk_bf16(p2, p3);
                int phys = (2 * nt + (quad >> 1)) ^ (lr & 7);
                *(u32x2_ma*)(Pt + prow * 64 + phys * 8 + (quad & 1) * 4) = pw;
            }
        }

        // order P writes before P reads (same-wave DS pipe is in-order)
        asm volatile("" ::: "memory");

        // O^T += V^T.P^T  (A = V^T frag, B = P^T frag)
        #pragma unroll
        for (int kc2 = 0; kc2 < 2; kc2++) {
            short8 pf[2];
            int pp = ((4 * kc2 + quad) ^ (lr & 7)) * 8;
            #pragma unroll
            for (int mt = 0; mt < 2; mt++)
                pf[mt] = *(const short8_ma*)(Pt + (w * 32 + mt * 16 + lr) * 64 + pp);
            #pragma unroll
            for (int mt = 0; mt < 2; mt++)
                #pragma unroll
                for (int dn = 0; dn < 4; dn++)
                    oacc[mt][dn] = mfma16x16x32(vf[kc2][dn], pf[mt], oacc[mt][dn]);
        }
        // order this kt's P reads before next kt's overwriting P writes
        asm volatile("" ::: "memory");
    }

    // Epilogue: reduce l across the 4 quads holding each qrow, normalize,
    // transpose O^T through LDS, store coalesced.
    #pragma unroll
    for (int mt = 0; mt < 2; mt++) {
        lsum[mt] += __shfl_xor(lsum[mt], 16, 64);
        lsum[mt] += __shfl_xor(lsum[mt], 32, 64);
    }
    ushort_t* Ot = Pt;  // reuse; rows are wave-private (qrows w*32..w*32+31)
    float inv[2] = { 1.f / lsum[0], 1.f / lsum[1] };
    asm volatile("" ::: "memory");
    #pragma unroll
    for (int mt = 0; mt < 2; mt++)
        #pragma unroll
        for (int dn = 0; dn < 4; dn++) {
            u32x2 pw;
            pw[0] = cvtpk_bf16(oacc[mt][dn][0] * inv[mt], oacc[mt][dn][1] * inv[mt]);
            pw[1] = cvtpk_bf16(oacc[mt][dn][2] * inv[mt], oacc[mt][dn][3] * inv[mt]);
            int phys = (2 * dn + (quad >> 1)) ^ (lr & 7);
            *(u32x2_ma*)(Ot + (w * 32 + mt * 16 + lr) * 64 + phys * 8 + (quad & 1) * 4) = pw;
        }
    asm volatile("" ::: "memory");
    {
        int qrow = t >> 1;            // wave w reads back its own rows 32w..32w+31
        int dhalf = (t & 1) * 32;
        #pragma unroll
        for (int cc = 0; cc < 4; cc++) {
            int phys = ((4 * (t & 1) + cc) ^ (qrow & 7)) * 8;
            short8 v = *(const short8_ma*)(Ot + qrow * 64 + phys);
            *(short8_ma*)(Z + qbase + (size_t)qrow * rs + dhalf + cc * 8) = v;
        }
    }
}

// ---------------------------------------------------------------------------
extern "C" void kernel_launch(void* const* d_in, const int* in_sizes, int n_in,
                              void* d_out, int out_size, void* d_ws, size_t ws_size,
                              hipStream_t stream) {
    const float* query = (const float*)d_in[0];
    const float* key   = (const float*)d_in[1];
    const float* value = (const float*)d_in[2];
    const float* Wq = (const float*)d_in[3];
    const float* bq = (const float*)d_in[4];
    const float* Wk = (const float*)d_in[5];
    const float* bk = (const float*)d_in[6];
    const float* Wv = (const float*)d_in[7];
    const float* bv = (const float*)d_in[8];
    const float* Wo = (const float*)d_in[9];
    const float* bo = (const float*)d_in[10];
    float* out = (float*)d_out;

    char* ws = (char*)d_ws;
    const size_t WSZ = 1024ull * 1024 * 2;
    const size_t QSZ = 8192ull * 1024 * 2;
    const size_t BW = 4 * WSZ;
    ushort_t* WqT = (ushort_t*)(ws + 0 * WSZ);
    ushort_t* WkT = (ushort_t*)(ws + 1 * WSZ);
    ushort_t* WvT = (ushort_t*)(ws + 2 * WSZ);
    ushort_t* WoT = (ushort_t*)(ws + 3 * WSZ);
    // Buffer lifetimes: S1: Qbf -> Kws; S2: Kbf -> VtG; S3: Vbf; S4: Qws (= Z)
    ushort_t* S1 = (ushort_t*)(ws + BW + 0 * QSZ);
    ushort_t* S2 = (ushort_t*)(ws + BW + 1 * QSZ);
    ushort_t* S3 = (ushort_t*)(ws + BW + 2 * QSZ);
    ushort_t* S4 = (ushort_t*)(ws + BW + 3 * QSZ);

    cast3<<<dim3(4096, 1, 3), 256, 0, stream>>>(query, key, value, S1, S2, S3);
    transpose4<<<dim3(16, 16, 4), 256, 0, stream>>>(Wq, Wk, Wv, Wo, WqT, WkT, WvT, WoT);

    dim3 gg(8, 64);
    // Q projection carries 1/sqrt(64) * log2(e): softmax runs in exp2 domain
    gemm_async<0><<<gg, 256, 0, stream>>>(S1, WqT, bq, S4, 8192, 1024, 1024, 0.125f * 1.4426950408889634f);
    gemm_async<0><<<gg, 256, 0, stream>>>(S2, WkT, bk, S1, 8192, 1024, 1024, 1.0f);
    // V projection writes VtG layout directly (vtrans fused into epilogue)
    gemm_async<2><<<gg, 256, 0, stream>>>(S3, WvT, bv, S2, 8192, 1024, 1024, 1.0f);

    attn_fwd<<<dim3(16, 64), 256, 0, stream>>>(S4, S1, S2, S4);

    gemm_async<1><<<gg, 256, 0, stream>>>(S4, WoT, bo, out, 8192, 1024, 1024, 1.0f);
}

// Round 6
// 343.969 us; speedup vs baseline: 1.5391x; 1.5391x over previous
//
#include <hip/hip_runtime.h>
#include <hip/hip_bf16.h>

typedef unsigned short ushort_t;
typedef unsigned int u32;
typedef __attribute__((ext_vector_type(8))) short short8;
typedef short8 __attribute__((may_alias)) short8_ma;
typedef __attribute__((ext_vector_type(4))) float f32x4;
typedef f32x4 __attribute__((may_alias)) f32x4_ma;
typedef __attribute__((ext_vector_type(2))) unsigned int u32x2;
typedef u32x2 __attribute__((may_alias)) u32x2_ma;
typedef __attribute__((ext_vector_type(4))) unsigned int u32x4;
typedef u32x4 __attribute__((may_alias)) u32x4_ma;

#if __has_builtin(__builtin_amdgcn_exp2f)
#define EXP2(x) __builtin_amdgcn_exp2f(x)
#else
#define EXP2(x) exp2f(x)
#endif

__device__ __forceinline__ unsigned short f2bf(float f) {
    union { float f; unsigned int i; } x; x.f = f;
    unsigned int r = x.i + 0x7FFFu + ((x.i >> 16) & 1u);
    return (unsigned short)(r >> 16);
}
__device__ __forceinline__ unsigned int bfround(float f) {
    union { float f; unsigned int i; } x; x.f = f;
    return x.i + 0x7FFFu + ((x.i >> 16) & 1u);
}
// RNE bf16 pair packed in u32: [lo, hi] in memory order.
__device__ __forceinline__ unsigned int pack2bf(float lo, float hi) {
    return __builtin_amdgcn_perm(bfround(hi), bfround(lo), 0x07060302u);
}
// Single-instruction packed f32->bf16 (RNE): dst.lo = bf16(lo), dst.hi = bf16(hi).
__device__ __forceinline__ u32 cvtpk_bf16(float lo, float hi) {
    u32 r;
    asm("v_cvt_pk_bf16_f32 %0, %1, %2" : "=v"(r) : "v"(lo), "v"(hi));
    return r;
}
__device__ __forceinline__ f32x4 mfma16x16x32(short8 a, short8 b, f32x4 c) {
    return __builtin_amdgcn_mfma_f32_16x16x32_bf16(a, b, c, 0, 0, 0);
}
// Async global->LDS, 16B per lane. LDS dest = (wave-uniform base) + lane*16.
typedef const __attribute__((address_space(1))) u32 gu32;
typedef __attribute__((address_space(3))) u32 lu32;
__device__ __forceinline__ void async16(const ushort_t* g, ushort_t* l) {
    __builtin_amdgcn_global_load_lds((gu32*)g, (lu32*)l, 16, 0, 0);
}

// ---------------------------------------------------------------------------
// cast3: f32 -> bf16, 8 elements/thread, 3 tensors via blockIdx.z
// ---------------------------------------------------------------------------
__global__ __launch_bounds__(256)
void cast3(const float* __restrict__ A0, const float* __restrict__ A1,
           const float* __restrict__ A2, ushort_t* __restrict__ O0,
           ushort_t* __restrict__ O1, ushort_t* __restrict__ O2) {
    const float* A; ushort_t* O;
    switch (blockIdx.z) {
        case 0: A = A0; O = O0; break;
        case 1: A = A1; O = O1; break;
        default: A = A2; O = O2; break;
    }
    size_t idx = ((size_t)blockIdx.x * 256 + threadIdx.x) * 8;
    f32x4 v0 = *(const f32x4_ma*)(A + idx);
    f32x4 v1 = *(const f32x4_ma*)(A + idx + 4);
    u32x4 pk;
    pk[0] = pack2bf(v0[0], v0[1]);
    pk[1] = pack2bf(v0[2], v0[3]);
    pk[2] = pack2bf(v1[0], v1[1]);
    pk[3] = pack2bf(v1[2], v1[3]);
    *(u32x4_ma*)(O + idx) = pk;
}

// ---------------------------------------------------------------------------
// Weight transpose + f32->bf16: Wt[n][k] = bf16(W[k][n]), 1024x1024, 4 matrices
// ---------------------------------------------------------------------------
__global__ __launch_bounds__(256)
void transpose4(const float* __restrict__ W0, const float* __restrict__ W1,
                const float* __restrict__ W2, const float* __restrict__ W3,
                ushort_t* __restrict__ T0, ushort_t* __restrict__ T1,
                ushort_t* __restrict__ T2, ushort_t* __restrict__ T3) {
    __shared__ ushort_t tile[64][65];
    const float* W; ushort_t* T;
    switch (blockIdx.z) {
        case 0: W = W0; T = T0; break;
        case 1: W = W1; T = T1; break;
        case 2: W = W2; T = T2; break;
        default: W = W3; T = T3; break;
    }
    int bx = blockIdx.x * 64, by = blockIdx.y * 64;
    int tx = threadIdx.x & 63, ty = threadIdx.x >> 6;
    #pragma unroll
    for (int i = 0; i < 64; i += 4)
        tile[ty + i][tx] = f2bf(W[(size_t)(by + ty + i) * 1024 + bx + tx]);
    __syncthreads();
    #pragma unroll
    for (int i = 0; i < 64; i += 4)
        T[(size_t)(bx + ty + i) * 1024 + by + tx] = tile[tx][ty + i];
}

// ---------------------------------------------------------------------------
// GEMM (all-bf16 inputs): C[M,N] = A[M,K] @ Bt[N,K]^T + bias[N]
// Same verified structure as R4 (2-phase dbuf, global_load_lds, chunk^row&7
// swizzle, T1 XCD-chunked block swizzle), re-tiled to 8 waves / 512 threads:
// wave owns 32x64 (acc[2][4]); staging split 8 ways. LDS 64KB -> 2 blocks/CU
// = 16 waves/CU = 4/SIMD (was 2/SIMD) -> latency hiding via TLP.
// MODE: 0 = bf16 C (outscale), 1 = f32 C, 2 = bf16 C^T scattered into
//   VtG[(b*16+h)*64+d][kr] (vtrans fused into the epilogue).
// ---------------------------------------------------------------------------
template<int MODE>
__global__ __launch_bounds__(512)
void gemm_async(const ushort_t* __restrict__ A, const ushort_t* __restrict__ Bt,
                const float* __restrict__ bias, void* __restrict__ Cab,
                int M, int N, int K, float outscale) {
    __shared__ __align__(16) ushort_t As[2][128 * 64];
    __shared__ __align__(16) ushort_t Bs[2][128 * 64];
    const int t = threadIdx.x;
    // grid is (8, 64): old = dispatch index; XCD = old & 7 (round-robin).
    const int old = blockIdx.x + (blockIdx.y << 3);
    const int neu = ((old & 7) << 6) | (old >> 3);   // bijective, 512 blocks
    const int n0 = (neu & 7) * 128, m0 = (neu >> 3) * 128;
    const int w = t >> 6, lane = t & 63, quad = lane >> 4, lr = lane & 15;
    const int wm = (w & 3) * 32, wn = (w >> 2) * 64;
    const int lrow8 = lane >> 3, lchunk = lane & 7;
    const int sw = (lchunk ^ lrow8) * 8;

    f32x4 acc[2][4] = {};

    #define STAGEAB(dst, koff) do { \
        _Pragma("unroll") \
        for (int i_ = 0; i_ < 2; i_++) { \
            int ra_ = 16 * w + 8 * i_ + lrow8; \
            async16(A  + (size_t)(m0 + ra_) * K + (koff) + sw, &As[dst][(16 * w + 8 * i_) * 64]); \
            async16(Bt + (size_t)(n0 + ra_) * K + (koff) + sw, &Bs[dst][(16 * w + 8 * i_) * 64]); \
        } } while (0)

    STAGEAB(0, 0);

    int cur = 0;
    for (int k0 = 0; k0 < K; k0 += 64) {
        __syncthreads();   // drains vmcnt: buf[cur] ready
        if (k0 + 64 < K)
            STAGEAB(cur ^ 1, k0 + 64);
        #pragma unroll
        for (int kc = 0; kc < 2; kc++) {
            short8 af[2], bf[4];
            int pa = ((4 * kc + quad) ^ (lr & 7)) * 8;
            #pragma unroll
            for (int i = 0; i < 2; i++)
                af[i] = *(const short8_ma*)(As[cur] + (wm + i * 16 + lr) * 64 + pa);
            #pragma unroll
            for (int j = 0; j < 4; j++)
                bf[j] = *(const short8_ma*)(Bs[cur] + (wn + j * 16 + lr) * 64 + pa);
            #pragma unroll
            for (int i = 0; i < 2; i++)
                #pragma unroll
                for (int j = 0; j < 4; j++)
                    acc[i][j] = mfma16x16x32(af[i], bf[j], acc[i][j]);
        }
        cur ^= 1;
    }
    #undef STAGEAB

    // Epilogue: C/D layout row = quad*4 + reg, col = lane&15
    #pragma unroll
    for (int i = 0; i < 2; i++) {
        int row = m0 + wm + i * 16 + quad * 4;
        #pragma unroll
        for (int j = 0; j < 4; j++) {
            int col = n0 + wn + j * 16 + lr;
            float bv = bias[col];
            if (MODE == 2) {
                // VtG[(b*16 + h)*64 + d][kr], b=row>>11, kr=row&2047,
                // h=col>>6, d=col&63. r=0..3 are consecutive kr.
                u32x2 pw;
                pw[0] = cvtpk_bf16(acc[i][j][0] + bv, acc[i][j][1] + bv);
                pw[1] = cvtpk_bf16(acc[i][j][2] + bv, acc[i][j][3] + bv);
                size_t vrow = (size_t)(((row >> 11) << 4) | (col >> 6)) * 64 + (col & 63);
                *(u32x2_ma*)((ushort_t*)Cab + vrow * 2048 + (row & 2047)) = pw;
            } else {
                #pragma unroll
                for (int r = 0; r < 4; r++) {
                    size_t idx = (size_t)(row + r) * N + col;
                    if (MODE == 1) ((float*)Cab)[idx] = acc[i][j][r] + bv;
                    else ((ushort_t*)Cab)[idx] = f2bf((acc[i][j][r] + bv) * outscale);
                }
            }
        }
    }
}

// ---------------------------------------------------------------------------
// Flash attention, static-max, 8-wave variant.
// R5's zero-staging regressed 2.7x (direct K/V reads = 16-line gathers ->
// TA request-rate bound; staging's value is COALESCING, not bandwidth).
// Reverted to R4's verified staged structure (K/V dbuf via global_load_lds,
// single barrier per kt, static-max softmax), re-tiled to 8 waves / 512
// threads: wave owns 16 qrows, staging split 8 ways (1 K + 1 V async16/wave).
// LDS unchanged 48KB -> 2-3 blocks/CU of 8 waves = 4-6 waves/SIMD (was 2).
// ---------------------------------------------------------------------------
__global__ __launch_bounds__(512)
void attn_fwd(const ushort_t* __restrict__ Q, const ushort_t* __restrict__ Kg,
              const ushort_t* __restrict__ VtG, ushort_t* __restrict__ Z) {
    __shared__ __align__(16) ushort_t Ks[2][64 * 64];   // [buf][krow][d]
    __shared__ __align__(16) ushort_t Vt[2][64 * 64];   // [buf][d][krow]
    __shared__ __align__(16) ushort_t Pt[128 * 64];     // [qrow][krow] (wave-private rows)

    const int t = threadIdx.x;
    // grid is (16, 64): old = dispatch index; XCD = old & 7.
    const int old = blockIdx.x + (blockIdx.y << 4);
    const int neu = ((old & 7) << 7) | (old >> 3);   // bijective, 1024 blocks
    const int qt = neu & 15;          // 0..15
    const int bh = neu >> 4;          // 0..63
    const int b = bh >> 4, h = bh & 15;
    const int w = t >> 6, lane = t & 63, quad = lane >> 4, lr = lane & 15;
    const int lrow8 = lane >> 3, lchunk = lane & 7;

    const size_t rs = 1024;
    const size_t qbase = ((size_t)b * 2048 + qt * 128) * rs + h * 64;
    const size_t kvbase = ((size_t)b * 2048) * rs + h * 64;
    const size_t vbase = (size_t)bh * 64 * 2048;

    // Q fragments (B-operand of S^T: n = lr = qrow, k = quad*8+j = d)
    // wave owns qrows w*16 .. w*16+15
    short8 qf[2];
    #pragma unroll
    for (int kc = 0; kc < 2; kc++)
        qf[kc] = *(const short8_ma*)(Q + qbase + (size_t)(w * 16 + lr) * rs + kc * 32 + quad * 8);

    f32x4 oacc[4] = {};      // oacc[dn] = O^T[d = dn*16+quad*4+r][qrow = w*16+lr]
    float lsum = 0.f;        // per-lane partial of sum(P) (reduced in epilogue)

    const int rloc0 = 8 * w + lrow8;           // rloc&7 == lrow8
    const int sw = (lchunk ^ lrow8) * 8;

    // prologue: stage kt=0 into buffer 0 (each wave stages 8 K-rows + 8 V-rows)
    async16(Kg + kvbase + (size_t)rloc0 * rs + sw, &Ks[0][(8 * w) * 64]);
    async16(VtG + vbase + (size_t)rloc0 * 2048 + sw, &Vt[0][(8 * w) * 64]);

    int cur = 0;
    for (int kt = 0; kt < 32; kt++) {
        __syncthreads();   // buf[cur] ready
        if (kt < 31) {
            int nxt = cur ^ 1;
            async16(Kg + kvbase + (size_t)((kt + 1) * 64 + rloc0) * rs + sw, &Ks[nxt][(8 * w) * 64]);
            async16(VtG + vbase + (size_t)rloc0 * 2048 + (kt + 1) * 64 + sw, &Vt[nxt][(8 * w) * 64]);
        }
        const ushort_t* Kc = Ks[cur];
        const ushort_t* Vc = Vt[cur];

        // S^T = K.Q^T : sacc[nt] rows = krow (nt*16+quad*4+r), cols = qrow (w*16+lr)
        f32x4 sacc[4] = {};
        #pragma unroll
        for (int kc = 0; kc < 2; kc++) {
            short8 kf[4];
            int pa = ((4 * kc + quad) ^ (lr & 7)) * 8;
            #pragma unroll
            for (int nt = 0; nt < 4; nt++)
                kf[nt] = *(const short8_ma*)(Kc + (nt * 16 + lr) * 64 + pa);
            #pragma unroll
            for (int nt = 0; nt < 4; nt++)
                sacc[nt] = mfma16x16x32(kf[nt], qf[kc], sacc[nt]);
        }

        // static-max softmax: P = exp2(s) directly; no cross-lane ops, no branch
        {
            const int prow = w * 16 + lr;
            #pragma unroll
            for (int nt = 0; nt < 4; nt++) {
                float p0 = EXP2(sacc[nt][0]);
                float p1 = EXP2(sacc[nt][1]);
                float p2 = EXP2(sacc[nt][2]);
                float p3 = EXP2(sacc[nt][3]);
                lsum += (p0 + p1) + (p2 + p3);
                u32x2 pw;
                pw[0] = cvtpk_bf16(p0, p1);
                pw[1] = cvtpk_bf16(p2, p3);
                int phys = (2 * nt + (quad >> 1)) ^ (lr & 7);
                *(u32x2_ma*)(Pt + prow * 64 + phys * 8 + (quad & 1) * 4) = pw;
            }
        }

        // order P writes before P reads (same-wave DS pipe is in-order)
        asm volatile("" ::: "memory");

        // O^T += V^T.P^T  (A = V^T frag, B = P^T frag)
        #pragma unroll
        for (int kc2 = 0; kc2 < 2; kc2++) {
            int pp = ((4 * kc2 + quad) ^ (lr & 7)) * 8;
            short8 pf = *(const short8_ma*)(Pt + (w * 16 + lr) * 64 + pp);
            #pragma unroll
            for (int dn = 0; dn < 4; dn++) {
                short8 vf = *(const short8_ma*)(Vc + (dn * 16 + lr) * 64 + pp);
                oacc[dn] = mfma16x16x32(vf, pf, oacc[dn]);
            }
        }
        // order this kt's P reads before next kt's overwriting P writes
        asm volatile("" ::: "memory");
        cur ^= 1;
    }

    // Epilogue: reduce l across the 4 quads holding each qrow, normalize,
    // transpose O^T through LDS (Pt reuse, wave-private rows), store coalesced.
    lsum += __shfl_xor(lsum, 16, 64);
    lsum += __shfl_xor(lsum, 32, 64);
    ushort_t* Ot = Pt;
    float inv = 1.f / lsum;
    asm volatile("" ::: "memory");
    #pragma unroll
    for (int dn = 0; dn < 4; dn++) {
        u32x2 pw;
        pw[0] = cvtpk_bf16(oacc[dn][0] * inv, oacc[dn][1] * inv);
        pw[1] = cvtpk_bf16(oacc[dn][2] * inv, oacc[dn][3] * inv);
        int phys = (2 * dn + (quad >> 1)) ^ (lr & 7);
        *(u32x2_ma*)(Ot + (w * 16 + lr) * 64 + phys * 8 + (quad & 1) * 4) = pw;
    }
    asm volatile("" ::: "memory");
    {
        int qrow = t >> 2;            // wave w reads back its own rows 16w..16w+15
        #pragma unroll
        for (int cc = 0; cc < 2; cc++) {
            int c2 = (t & 3) * 2 + cc;
            int phys = (c2 ^ (qrow & 7)) * 8;
            short8 v = *(const short8_ma*)(Ot + qrow * 64 + phys);
            *(short8_ma*)(Z + qbase + (size_t)qrow * rs + c2 * 8) = v;
        }
    }
}

// ---------------------------------------------------------------------------
extern "C" void kernel_launch(void* const* d_in, const int* in_sizes, int n_in,
                              void* d_out, int out_size, void* d_ws, size_t ws_size,
                              hipStream_t stream) {
    const float* query = (const float*)d_in[0];
    const float* key   = (const float*)d_in[1];
    const float* value = (const float*)d_in[2];
    const float* Wq = (const float*)d_in[3];
    const float* bq = (const float*)d_in[4];
    const float* Wk = (const float*)d_in[5];
    const float* bk = (const float*)d_in[6];
    const float* Wv = (const float*)d_in[7];
    const float* bv = (const float*)d_in[8];
    const float* Wo = (const float*)d_in[9];
    const float* bo = (const float*)d_in[10];
    float* out = (float*)d_out;

    char* ws = (char*)d_ws;
    const size_t WSZ = 1024ull * 1024 * 2;
    const size_t QSZ = 8192ull * 1024 * 2;
    const size_t BW = 4 * WSZ;
    ushort_t* WqT = (ushort_t*)(ws + 0 * WSZ);
    ushort_t* WkT = (ushort_t*)(ws + 1 * WSZ);
    ushort_t* WvT = (ushort_t*)(ws + 2 * WSZ);
    ushort_t* WoT = (ushort_t*)(ws + 3 * WSZ);
    // Buffer lifetimes: S1: Qbf -> Kws; S2: Kbf -> VtG; S3: Vbf; S4: Qws (= Z)
    ushort_t* S1 = (ushort_t*)(ws + BW + 0 * QSZ);
    ushort_t* S2 = (ushort_t*)(ws + BW + 1 * QSZ);
    ushort_t* S3 = (ushort_t*)(ws + BW + 2 * QSZ);
    ushort_t* S4 = (ushort_t*)(ws + BW + 3 * QSZ);

    cast3<<<dim3(4096, 1, 3), 256, 0, stream>>>(query, key, value, S1, S2, S3);
    transpose4<<<dim3(16, 16, 4), 256, 0, stream>>>(Wq, Wk, Wv, Wo, WqT, WkT, WvT, WoT);

    dim3 gg(8, 64);
    // Q projection carries 1/sqrt(64) * log2(e): softmax runs in exp2 domain
    gemm_async<0><<<gg, 512, 0, stream>>>(S1, WqT, bq, S4, 8192, 1024, 1024, 0.125f * 1.4426950408889634f);
    gemm_async<0><<<gg, 512, 0, stream>>>(S2, WkT, bk, S1, 8192, 1024, 1024, 1.0f);
    // V projection writes VtG layout directly (vtrans fused into epilogue)
    gemm_async<2><<<gg, 512, 0, stream>>>(S3, WvT, bv, S2, 8192, 1024, 1024, 1.0f);

    attn_fwd<<<dim3(16, 64), 512, 0, stream>>>(S4, S1, S2, S4);

    gemm_async<1><<<gg, 512, 0, stream>>>(S4, WoT, bo, out, 8192, 1024, 1024, 1.0f);
}

// Round 7
// 326.957 us; speedup vs baseline: 1.6192x; 1.0520x over previous
//
#include <hip/hip_runtime.h>
#include <hip/hip_bf16.h>

typedef unsigned short ushort_t;
typedef unsigned int u32;
typedef __attribute__((ext_vector_type(8))) short short8;
typedef short8 __attribute__((may_alias)) short8_ma;
typedef __attribute__((ext_vector_type(4))) float f32x4;
typedef f32x4 __attribute__((may_alias)) f32x4_ma;
typedef __attribute__((ext_vector_type(2))) unsigned int u32x2;
typedef u32x2 __attribute__((may_alias)) u32x2_ma;
typedef __attribute__((ext_vector_type(4))) unsigned int u32x4;
typedef u32x4 __attribute__((may_alias)) u32x4_ma;

#if __has_builtin(__builtin_amdgcn_exp2f)
#define EXP2(x) __builtin_amdgcn_exp2f(x)
#else
#define EXP2(x) exp2f(x)
#endif

__device__ __forceinline__ unsigned short f2bf(float f) {
    union { float f; unsigned int i; } x; x.f = f;
    unsigned int r = x.i + 0x7FFFu + ((x.i >> 16) & 1u);
    return (unsigned short)(r >> 16);
}
__device__ __forceinline__ unsigned int bfround(float f) {
    union { float f; unsigned int i; } x; x.f = f;
    return x.i + 0x7FFFu + ((x.i >> 16) & 1u);
}
// RNE bf16 pair packed in u32: [lo, hi] in memory order.
__device__ __forceinline__ unsigned int pack2bf(float lo, float hi) {
    return __builtin_amdgcn_perm(bfround(hi), bfround(lo), 0x07060302u);
}
// Single-instruction packed f32->bf16 (RNE): dst.lo = bf16(lo), dst.hi = bf16(hi).
__device__ __forceinline__ u32 cvtpk_bf16(float lo, float hi) {
    u32 r;
    asm("v_cvt_pk_bf16_f32 %0, %1, %2" : "=v"(r) : "v"(lo), "v"(hi));
    return r;
}
__device__ __forceinline__ f32x4 mfma16x16x32(short8 a, short8 b, f32x4 c) {
    return __builtin_amdgcn_mfma_f32_16x16x32_bf16(a, b, c, 0, 0, 0);
}
// Async global->LDS, 16B per lane. LDS dest = (wave-uniform base) + lane*16.
typedef const __attribute__((address_space(1))) u32 gu32;
typedef __attribute__((address_space(3))) u32 lu32;
__device__ __forceinline__ void async16(const ushort_t* g, ushort_t* l) {
    __builtin_amdgcn_global_load_lds((gu32*)g, (lu32*)l, 16, 0, 0);
}

// ---------------------------------------------------------------------------
// cast3: f32 -> bf16, 8 elements/thread, 3 tensors via blockIdx.z
// ---------------------------------------------------------------------------
__global__ __launch_bounds__(256)
void cast3(const float* __restrict__ A0, const float* __restrict__ A1,
           const float* __restrict__ A2, ushort_t* __restrict__ O0,
           ushort_t* __restrict__ O1, ushort_t* __restrict__ O2) {
    const float* A; ushort_t* O;
    switch (blockIdx.z) {
        case 0: A = A0; O = O0; break;
        case 1: A = A1; O = O1; break;
        default: A = A2; O = O2; break;
    }
    size_t idx = ((size_t)blockIdx.x * 256 + threadIdx.x) * 8;
    f32x4 v0 = *(const f32x4_ma*)(A + idx);
    f32x4 v1 = *(const f32x4_ma*)(A + idx + 4);
    u32x4 pk;
    pk[0] = pack2bf(v0[0], v0[1]);
    pk[1] = pack2bf(v0[2], v0[3]);
    pk[2] = pack2bf(v1[0], v1[1]);
    pk[3] = pack2bf(v1[2], v1[3]);
    *(u32x4_ma*)(O + idx) = pk;
}

// ---------------------------------------------------------------------------
// Weight transpose + f32->bf16: Wt[n][k] = bf16(W[k][n]), 1024x1024, 4 matrices
// ---------------------------------------------------------------------------
__global__ __launch_bounds__(256)
void transpose4(const float* __restrict__ W0, const float* __restrict__ W1,
                const float* __restrict__ W2, const float* __restrict__ W3,
                ushort_t* __restrict__ T0, ushort_t* __restrict__ T1,
                ushort_t* __restrict__ T2, ushort_t* __restrict__ T3) {
    __shared__ ushort_t tile[64][65];
    const float* W; ushort_t* T;
    switch (blockIdx.z) {
        case 0: W = W0; T = T0; break;
        case 1: W = W1; T = T1; break;
        case 2: W = W2; T = T2; break;
        default: W = W3; T = T3; break;
    }
    int bx = blockIdx.x * 64, by = blockIdx.y * 64;
    int tx = threadIdx.x & 63, ty = threadIdx.x >> 6;
    #pragma unroll
    for (int i = 0; i < 64; i += 4)
        tile[ty + i][tx] = f2bf(W[(size_t)(by + ty + i) * 1024 + bx + tx]);
    __syncthreads();
    #pragma unroll
    for (int i = 0; i < 64; i += 4)
        T[(size_t)(bx + ty + i) * 1024 + by + tx] = tile[tx][ty + i];
}

// ---------------------------------------------------------------------------
// GEMM (all-bf16 inputs): C[M,N] = A[M,K] @ Bt[N,K]^T + bias[N]
// R4-verified structure: 256 threads / 4 waves, 2-phase dbuf, global_load_lds,
// chunk^row&7 swizzle, T1 XCD-chunked block swizzle (XCD k owns M-panels
// [8k,8k+8) x all N-tiles; A+B L2-resident). R6's 8-wave retile regressed
// ~5% (worse MFMA:ds_read ratio) -> reverted.
// MODE: 0 = bf16 C (outscale), 1 = f32 C, 2 = bf16 C^T scattered into
//   VtG[(b*16+h)*64+d][kr] (vtrans fused into the epilogue).
// ---------------------------------------------------------------------------
template<int MODE>
__global__ __launch_bounds__(256)
void gemm_async(const ushort_t* __restrict__ A, const ushort_t* __restrict__ Bt,
                const float* __restrict__ bias, void* __restrict__ Cab,
                int M, int N, int K, float outscale) {
    __shared__ __align__(16) ushort_t As[2][128 * 64];
    __shared__ __align__(16) ushort_t Bs[2][128 * 64];
    const int t = threadIdx.x;
    // grid is (8, 64): old = dispatch index; XCD = old & 7 (round-robin).
    const int old = blockIdx.x + (blockIdx.y << 3);
    const int neu = ((old & 7) << 6) | (old >> 3);   // bijective, 512 blocks
    const int n0 = (neu & 7) * 128, m0 = (neu >> 3) * 128;
    const int w = t >> 6, lane = t & 63, quad = lane >> 4, lr = lane & 15;
    const int wm = (w >> 1) * 64, wn = (w & 1) * 64;
    const int lrow8 = lane >> 3, lchunk = lane & 7;
    const int sw = (lchunk ^ lrow8) * 8;

    f32x4 acc[4][4] = {};

    #define STAGEAB(dst, koff) do { \
        _Pragma("unroll") \
        for (int i_ = 0; i_ < 4; i_++) { \
            int ra_ = 32 * w + 8 * i_ + lrow8; \
            async16(A  + (size_t)(m0 + ra_) * K + (koff) + sw, &As[dst][(32 * w + 8 * i_) * 64]); \
            async16(Bt + (size_t)(n0 + ra_) * K + (koff) + sw, &Bs[dst][(32 * w + 8 * i_) * 64]); \
        } } while (0)

    STAGEAB(0, 0);

    int cur = 0;
    for (int k0 = 0; k0 < K; k0 += 64) {
        __syncthreads();   // drains vmcnt: buf[cur] ready
        if (k0 + 64 < K)
            STAGEAB(cur ^ 1, k0 + 64);
        #pragma unroll
        for (int kc = 0; kc < 2; kc++) {
            short8 af[4], bf[4];
            int pa = ((4 * kc + quad) ^ (lr & 7)) * 8;
            #pragma unroll
            for (int i = 0; i < 4; i++) {
                af[i] = *(const short8_ma*)(As[cur] + (wm + i * 16 + lr) * 64 + pa);
                bf[i] = *(const short8_ma*)(Bs[cur] + (wn + i * 16 + lr) * 64 + pa);
            }
            #pragma unroll
            for (int i = 0; i < 4; i++)
                #pragma unroll
                for (int j = 0; j < 4; j++)
                    acc[i][j] = mfma16x16x32(af[i], bf[j], acc[i][j]);
        }
        cur ^= 1;
    }
    #undef STAGEAB

    // Epilogue: C/D layout row = quad*4 + reg, col = lane&15
    #pragma unroll
    for (int i = 0; i < 4; i++) {
        int row = m0 + wm + i * 16 + quad * 4;
        #pragma unroll
        for (int j = 0; j < 4; j++) {
            int col = n0 + wn + j * 16 + lr;
            float bv = bias[col];
            if (MODE == 2) {
                // VtG[(b*16 + h)*64 + d][kr], b=row>>11, kr=row&2047,
                // h=col>>6, d=col&63. r=0..3 are consecutive kr.
                u32x2 pw;
                pw[0] = cvtpk_bf16(acc[i][j][0] + bv, acc[i][j][1] + bv);
                pw[1] = cvtpk_bf16(acc[i][j][2] + bv, acc[i][j][3] + bv);
                size_t vrow = (size_t)(((row >> 11) << 4) | (col >> 6)) * 64 + (col & 63);
                *(u32x2_ma*)((ushort_t*)Cab + vrow * 2048 + (row & 2047)) = pw;
            } else {
                #pragma unroll
                for (int r = 0; r < 4; r++) {
                    size_t idx = (size_t)(row + r) * N + col;
                    if (MODE == 1) ((float*)Cab)[idx] = acc[i][j][r] + bv;
                    else ((ushort_t*)Cab)[idx] = f2bf((acc[i][j][r] + bv) * outscale);
                }
            }
        }
    }
}

// ---------------------------------------------------------------------------
// Flash attention, static-max, 8-wave, QBLK=256.
// R6 ledger: per kt per wave 26 DS wave-ops vs 16 MFMA -> DS-issue dominated;
// VGPR only 40. This round: each block owns 256 qrows (wave owns 32 = mt
// loop, the R4-verified body), so kf/vf reads, staging, and barriers amortize
// over 2x the work (36 DS-ops per 32 MFMA, -30%; barriers/qrow halved).
// LDS 64KB (Pt 256 rows) -> 2 blocks x 8 waves = 16 waves/CU (unchanged).
// launch_bounds(512,4) caps VGPR at 128 to guarantee co-residency.
// ---------------------------------------------------------------------------
__global__ __launch_bounds__(512, 4)
void attn_fwd(const ushort_t* __restrict__ Q, const ushort_t* __restrict__ Kg,
              const ushort_t* __restrict__ VtG, ushort_t* __restrict__ Z) {
    __shared__ __align__(16) ushort_t Ks[2][64 * 64];   // [buf][krow][d]   16 KB
    __shared__ __align__(16) ushort_t Vt[2][64 * 64];   // [buf][d][krow]   16 KB
    __shared__ __align__(16) ushort_t Pt[256 * 64];     // [qrow][krow]     32 KB

    const int t = threadIdx.x;
    // grid is (8, 64): old = dispatch index; XCD = old & 7.
    const int old = blockIdx.x + (blockIdx.y << 3);
    const int neu = ((old & 7) << 6) | (old >> 3);   // bijective, 512 blocks
    const int qt = neu & 7;           // 0..7 (256-row Q tiles)
    const int bh = neu >> 3;          // 0..63
    const int b = bh >> 4, h = bh & 15;
    const int w = t >> 6, lane = t & 63, quad = lane >> 4, lr = lane & 15;
    const int lrow8 = lane >> 3, lchunk = lane & 7;

    const size_t rs = 1024;
    const size_t qbase = ((size_t)b * 2048 + qt * 256) * rs + h * 64;
    const size_t kvbase = ((size_t)b * 2048) * rs + h * 64;
    const size_t vbase = (size_t)bh * 64 * 2048;

    // Q fragments (B-operand of S^T: n = lr = qrow, k = quad*8+j = d)
    // wave owns qrows w*32 + mt*16 + lr, mt in {0,1}
    short8 qf[2][2];
    #pragma unroll
    for (int mt = 0; mt < 2; mt++)
        #pragma unroll
        for (int kc = 0; kc < 2; kc++)
            qf[mt][kc] = *(const short8_ma*)(Q + qbase + (size_t)(w * 32 + mt * 16 + lr) * rs + kc * 32 + quad * 8);

    f32x4 oacc[2][4] = {};   // oacc[mt][dn] = O^T[d = dn*16+quad*4+r][qrow = w*32+mt*16+lr]
    float lsum[2] = { 0.f, 0.f };   // per-lane partials of sum(P)

    const int rloc0 = 8 * w + lrow8;           // rloc0 & 7 == lrow8
    const int sw = (lchunk ^ lrow8) * 8;

    // prologue: stage kt=0 into buffer 0 (each wave stages 8 K-rows + 8 V-rows)
    async16(Kg + kvbase + (size_t)rloc0 * rs + sw, &Ks[0][(8 * w) * 64]);
    async16(VtG + vbase + (size_t)rloc0 * 2048 + sw, &Vt[0][(8 * w) * 64]);

    int cur = 0;
    for (int kt = 0; kt < 32; kt++) {
        __syncthreads();   // buf[cur] ready
        if (kt < 31) {
            int nxt = cur ^ 1;
            async16(Kg + kvbase + (size_t)((kt + 1) * 64 + rloc0) * rs + sw, &Ks[nxt][(8 * w) * 64]);
            async16(VtG + vbase + (size_t)rloc0 * 2048 + (kt + 1) * 64 + sw, &Vt[nxt][(8 * w) * 64]);
        }
        const ushort_t* Kc = Ks[cur];
        const ushort_t* Vc = Vt[cur];

        // S^T = K.Q^T : sacc[nt][mt] rows = krow (nt*16+quad*4+r), cols = qrow
        f32x4 sacc[4][2] = {};
        #pragma unroll
        for (int kc = 0; kc < 2; kc++) {
            short8 kf[4];
            int pa = ((4 * kc + quad) ^ (lr & 7)) * 8;
            #pragma unroll
            for (int nt = 0; nt < 4; nt++)
                kf[nt] = *(const short8_ma*)(Kc + (nt * 16 + lr) * 64 + pa);
            #pragma unroll
            for (int nt = 0; nt < 4; nt++)
                #pragma unroll
                for (int mt = 0; mt < 2; mt++)
                    sacc[nt][mt] = mfma16x16x32(kf[nt], qf[mt][kc], sacc[nt][mt]);
        }

        // static-max softmax: P = exp2(s) directly; no cross-lane ops, no branch
        #pragma unroll
        for (int mt = 0; mt < 2; mt++) {
            const int prow = w * 32 + mt * 16 + lr;
            #pragma unroll
            for (int nt = 0; nt < 4; nt++) {
                float p0 = EXP2(sacc[nt][mt][0]);
                float p1 = EXP2(sacc[nt][mt][1]);
                float p2 = EXP2(sacc[nt][mt][2]);
                float p3 = EXP2(sacc[nt][mt][3]);
                lsum[mt] += (p0 + p1) + (p2 + p3);
                u32x2 pw;
                pw[0] = cvtpk_bf16(p0, p1);
                pw[1] = cvtpk_bf16(p2, p3);
                int phys = (2 * nt + (quad >> 1)) ^ (lr & 7);
                *(u32x2_ma*)(Pt + prow * 64 + phys * 8 + (quad & 1) * 4) = pw;
            }
        }

        // order P writes before P reads (same-wave DS pipe is in-order)
        asm volatile("" ::: "memory");

        // O^T += V^T.P^T  (A = V^T frag, B = P^T frag)
        #pragma unroll
        for (int kc2 = 0; kc2 < 2; kc2++) {
            short8 pf[2], vf[4];
            int pp = ((4 * kc2 + quad) ^ (lr & 7)) * 8;
            #pragma unroll
            for (int mt = 0; mt < 2; mt++)
                pf[mt] = *(const short8_ma*)(Pt + (w * 32 + mt * 16 + lr) * 64 + pp);
            #pragma unroll
            for (int dn = 0; dn < 4; dn++)
                vf[dn] = *(const short8_ma*)(Vc + (dn * 16 + lr) * 64 + pp);
            #pragma unroll
            for (int mt = 0; mt < 2; mt++)
                #pragma unroll
                for (int dn = 0; dn < 4; dn++)
                    oacc[mt][dn] = mfma16x16x32(vf[dn], pf[mt], oacc[mt][dn]);
        }
        // order this kt's P reads before next kt's overwriting P writes
        asm volatile("" ::: "memory");
        cur ^= 1;
    }

    // Epilogue: reduce l across the 4 quads holding each qrow, normalize,
    // transpose O^T through LDS (Pt reuse, wave-private rows), store coalesced.
    #pragma unroll
    for (int mt = 0; mt < 2; mt++) {
        lsum[mt] += __shfl_xor(lsum[mt], 16, 64);
        lsum[mt] += __shfl_xor(lsum[mt], 32, 64);
    }
    ushort_t* Ot = Pt;
    float inv[2] = { 1.f / lsum[0], 1.f / lsum[1] };
    asm volatile("" ::: "memory");
    #pragma unroll
    for (int mt = 0; mt < 2; mt++)
        #pragma unroll
        for (int dn = 0; dn < 4; dn++) {
            u32x2 pw;
            pw[0] = cvtpk_bf16(oacc[mt][dn][0] * inv[mt], oacc[mt][dn][1] * inv[mt]);
            pw[1] = cvtpk_bf16(oacc[mt][dn][2] * inv[mt], oacc[mt][dn][3] * inv[mt]);
            int phys = (2 * dn + (quad >> 1)) ^ (lr & 7);
            *(u32x2_ma*)(Ot + (w * 32 + mt * 16 + lr) * 64 + phys * 8 + (quad & 1) * 4) = pw;
        }
    asm volatile("" ::: "memory");
    {
        int qrow = t >> 1;            // wave w reads back its own rows 32w..32w+31
        int dhalf = (t & 1) * 32;
        #pragma unroll
        for (int cc = 0; cc < 4; cc++) {
            int phys = ((4 * (t & 1) + cc) ^ (qrow & 7)) * 8;
            short8 v = *(const short8_ma*)(Ot + qrow * 64 + phys);
            *(short8_ma*)(Z + qbase + (size_t)qrow * rs + dhalf + cc * 8) = v;
        }
    }
}

// ---------------------------------------------------------------------------
extern "C" void kernel_launch(void* const* d_in, const int* in_sizes, int n_in,
                              void* d_out, int out_size, void* d_ws, size_t ws_size,
                              hipStream_t stream) {
    const float* query = (const float*)d_in[0];
    const float* key   = (const float*)d_in[1];
    const float* value = (const float*)d_in[2];
    const float* Wq = (const float*)d_in[3];
    const float* bq = (const float*)d_in[4];
    const float* Wk = (const float*)d_in[5];
    const float* bk = (const float*)d_in[6];
    const float* Wv = (const float*)d_in[7];
    const float* bv = (const float*)d_in[8];
    const float* Wo = (const float*)d_in[9];
    const float* bo = (const float*)d_in[10];
    float* out = (float*)d_out;

    char* ws = (char*)d_ws;
    const size_t WSZ = 1024ull * 1024 * 2;
    const size_t QSZ = 8192ull * 1024 * 2;
    const size_t BW = 4 * WSZ;
    ushort_t* WqT = (ushort_t*)(ws + 0 * WSZ);
    ushort_t* WkT = (ushort_t*)(ws + 1 * WSZ);
    ushort_t* WvT = (ushort_t*)(ws + 2 * WSZ);
    ushort_t* WoT = (ushort_t*)(ws + 3 * WSZ);
    // Buffer lifetimes: S1: Qbf -> Kws; S2: Kbf -> VtG; S3: Vbf; S4: Qws (= Z)
    ushort_t* S1 = (ushort_t*)(ws + BW + 0 * QSZ);
    ushort_t* S2 = (ushort_t*)(ws + BW + 1 * QSZ);
    ushort_t* S3 = (ushort_t*)(ws + BW + 2 * QSZ);
    ushort_t* S4 = (ushort_t*)(ws + BW + 3 * QSZ);

    cast3<<<dim3(4096, 1, 3), 256, 0, stream>>>(query, key, value, S1, S2, S3);
    transpose4<<<dim3(16, 16, 4), 256, 0, stream>>>(Wq, Wk, Wv, Wo, WqT, WkT, WvT, WoT);

    dim3 gg(8, 64);
    // Q projection carries 1/sqrt(64) * log2(e): softmax runs in exp2 domain
    gemm_async<0><<<gg, 256, 0, stream>>>(S1, WqT, bq, S4, 8192, 1024, 1024, 0.125f * 1.4426950408889634f);
    gemm_async<0><<<gg, 256, 0, stream>>>(S2, WkT, bk, S1, 8192, 1024, 1024, 1.0f);
    // V projection writes VtG layout directly (vtrans fused into epilogue)
    gemm_async<2><<<gg, 256, 0, stream>>>(S3, WvT, bv, S2, 8192, 1024, 1024, 1.0f);

    attn_fwd<<<dim3(8, 64), 512, 0, stream>>>(S4, S1, S2, S4);

    gemm_async<1><<<gg, 256, 0, stream>>>(S4, WoT, bo, out, 8192, 1024, 1024, 1.0f);
}